// Round 8
// baseline (334.099 us; speedup 1.0000x reference)
//
#include <hip/hip_runtime.h>
#include <stdint.h>

#define NBATCH 16
#define GRP 128
#define RADIX 1024
#define TILE 4096
#define TITEMS 16
#define SCAN_CHUNK 2048

typedef unsigned long long ull;

// XCD-aware swizzle: consecutive logical tiles -> same XCD (round-robin HW map).
__device__ __forceinline__ int xcd_swizzle(int blk, int G) {
  const int x = blk & 7, i = blk >> 3;
  const int q = G >> 3, r = G & 7;
  return x * q + (x < r ? x : r) + i;
}

// ---------------- setup ----------------

__global__ void setup_segments(const int* __restrict__ coords, int n,
                               int* __restrict__ bs, int* __restrict__ bsp,
                               int* __restrict__ num, int* __restrict__ nump) {
  __shared__ int st[NBATCH + 1];
  const int t = threadIdx.x;
  if (t <= NBATCH) {
    int lo = 0, hi = n;
    while (lo < hi) {
      const int mid = (lo + hi) >> 1;
      if (coords[4 * mid] < t) lo = mid + 1; else hi = mid;
    }
    st[t] = lo;
  }
  __syncthreads();
  if (t == 0) {
    int b = 0;
    for (int i = 0; i < NBATCH; ++i) {
      const int s = st[i];
      const int ni = st[i + 1] - s;
      bs[i] = s; bsp[i] = b; num[i] = ni;
      const int npi = (ni + GRP - 1) / GRP * GRP;
      nump[i] = npi;
      b += npi;
    }
    bs[NBATCH] = st[NBATCH];
    bsp[NBATCH] = b;
  }
}

// ---------------- keys (both sorts) + w2f + f2w + pass-0 hists ----------------

__global__ __launch_bounds__(256) void keys_both(
    const int* __restrict__ coords, const int* __restrict__ shape,
    const int* __restrict__ bs, const int* __restrict__ bsp,
    const int* __restrict__ num, const int* __restrict__ nump,
    ull* __restrict__ kx, ull* __restrict__ ky,
    int* __restrict__ win2flat, int* __restrict__ f2w,
    unsigned int* __restrict__ cx0, unsigned int* __restrict__ cy0,
    int n, int n_p, int nbh) {
  __shared__ int sbs[NBATCH + 1], sbsp[NBATCH + 1], snum[NBATCH], snump[NBATCH];
  __shared__ unsigned int hx[RADIX], hy[RADIX];
  const int tid = threadIdx.x;
  const int blk = blockIdx.x;
  if (tid <= NBATCH) { sbs[tid] = bs[tid]; sbsp[tid] = bsp[tid]; }
  if (tid < NBATCH) { snum[tid] = num[tid]; snump[tid] = nump[tid]; }
  for (int d = tid; d < RADIX; d += 256) { hx[d] = 0; hy[d] = 0; }
  __syncthreads();
  const int sz = shape[0], sy = shape[1], sx = shape[2];
  const int mx = ((sx + 15) >> 4) + 1;
  const int my = ((sy + 15) >> 4) + 1;
  const int mz = ((sz + 7) >> 3) + 1;
  const int mper = mx * my * mz;
  const int base = blk * TILE;
#pragma unroll 4
  for (int j = 0; j < TITEMS; ++j) {
    const int i = base + j * 256 + tid;
    if (i < n) {
      const int4 c = ((const int4*)coords)[i];
      const int b = c.x, z = c.y, y = c.z, x = c.w;
      const int wcx = x >> 4, cix = x & 15;
      const int wcy = y >> 4, ciy = y & 15;
      const int wcz = z >> 3, ciz = z & 7;
      const int bx = b * mper + wcx * (my * mz) + wcy * mz + wcz;
      const int by = b * mper + wcy * (mx * mz) + wcx * mz + wcz;
      const unsigned int keyx = (unsigned int)(bx * 2048 + cix * 128 + ciy * 8 + ciz);
      const unsigned int keyy = (unsigned int)(by * 2048 + ciy * 128 + cix * 8 + ciz);
      kx[i] = ((ull)keyx << 32) | (unsigned int)i;
      ky[i] = ((ull)keyy << 32) | (unsigned int)i;
      atomicAdd(&hx[keyx & (RADIX - 1)], 1u);
      atomicAdd(&hy[keyy & (RADIX - 1)], 1u);
      win2flat[i] = i + (sbsp[b] - sbs[b]);
    }
    if (i < n_p) {
      const int k = i;
      int b = 0;
#pragma unroll
      for (int jj = 1; jj < NBATCH; ++jj) b += (k >= sbsp[jj]) ? 1 : 0;
      const int bias = sbsp[b] - sbs[b];
      const int nb2 = snum[b], npb = snump[b];
      int val = k - bias;
      if (nb2 != npb && k >= sbsp[b] + nb2) {
        if (npb != GRP) {
          val = k - GRP - bias;
        } else {
          const int m = nb2 > 1 ? nb2 : 1;
          val = sbs[b] + (k - sbsp[b] - nb2) % m;
        }
      }
      f2w[k] = val;
    }
  }
  __syncthreads();
  if (blk < nbh)
    for (int d = tid; d < RADIX; d += 256) {
      cx0[(size_t)d * nbh + blk] = hx[d];
      cy0[(size_t)d * nbh + blk] = hy[d];
    }
}

// ---------------- per-block LDS histogram, both sorts ----------------

__global__ __launch_bounds__(256) void hist_both(
    const ull* __restrict__ sxp, const ull* __restrict__ syp,
    unsigned int* __restrict__ cx, unsigned int* __restrict__ cy,
    int n, int nbh, int shift) {
  __shared__ unsigned int h[RADIX];
  const int tid = threadIdx.x;
  const int half = (blockIdx.x >= nbh) ? 1 : 0;
  const int blk = blockIdx.x - half * nbh;
  const ull* __restrict__ src = half ? syp : sxp;
  unsigned int* __restrict__ counts = half ? cy : cx;
  for (int d = tid; d < RADIX; d += 256) h[d] = 0;
  __syncthreads();
  const int base = blk * TILE;
#pragma unroll 4
  for (int j = 0; j < TITEMS; ++j) {
    const int e = base + j * 256 + tid;
    if (e < n) {
      const ull p = src[e];
      atomicAdd(&h[(((unsigned int)(p >> 32)) >> shift) & (RADIX - 1)], 1u);
    }
  }
  __syncthreads();
  for (int d = tid; d < RADIX; d += 256)
    counts[(size_t)d * nbh + blk] = h[d];
}

// ---------------- chained exclusive scan, two independent halves ----------------

__device__ __forceinline__ unsigned int block_scan_excl(unsigned int thread_sum,
                                                        unsigned int* s) {
  const int tid = threadIdx.x;
  s[tid] = thread_sum;
  __syncthreads();
#pragma unroll
  for (int off = 1; off < 256; off <<= 1) {
    unsigned int x = (tid >= off) ? s[tid - off] : 0u;
    __syncthreads();
    s[tid] += x;
    __syncthreads();
  }
  return s[tid] - thread_sum;
}

__global__ void scan_both(unsigned int* __restrict__ cx, unsigned int* __restrict__ cy,
                          int L, int NS, ull* __restrict__ descx,
                          ull* __restrict__ descy) {
  __shared__ unsigned int s[256];
  __shared__ unsigned int s_base;
  const int tid = threadIdx.x;
  const int half = (blockIdx.x >= NS) ? 1 : 0;
  const int blk = blockIdx.x - half * NS;
  unsigned int* data = half ? cy : cx;
  ull* desc = half ? descy : descx;
  const int base = blk * SCAN_CHUNK + tid * 8;
  unsigned int v[8], sum = 0;
#pragma unroll
  for (int j = 0; j < 8; ++j) {
    const int idx = base + j;
    v[j] = (idx < L) ? data[idx] : 0u;
    sum += v[j];
  }
  const unsigned int excl = block_scan_excl(sum, s);
  const unsigned int total = s[255];
  if (tid == 0) {
    const ull tag = (blk == 0) ? (2ull << 32) : (1ull << 32);
    __hip_atomic_store(&desc[blk], tag | total, __ATOMIC_RELEASE,
                       __HIP_MEMORY_SCOPE_AGENT);
    if (blk == 0) s_base = 0;
  }
  if (blk > 0 && tid < 64) {
    unsigned int run = 0;
    int jb = blk - 1;
    for (;;) {
      const int j = jb - tid;
      ull d;
      if (j >= 0) {
        do {
          d = __hip_atomic_load(&desc[j], __ATOMIC_ACQUIRE, __HIP_MEMORY_SCOPE_AGENT);
        } while ((d >> 32) == 0);
      } else {
        d = (2ull << 32);
      }
      const ull m2 = __ballot((d >> 32) == 2);
      const int f = m2 ? __builtin_ctzll(m2) : 64;
      unsigned int contrib = (tid <= f) ? (unsigned int)d : 0u;
#pragma unroll
      for (int o = 32; o > 0; o >>= 1) contrib += __shfl_down(contrib, o, 64);
      run += __shfl(contrib, 0, 64);
      if (m2) break;
      jb -= 64;
    }
    if (tid == 0) {
      __hip_atomic_store(&desc[blk], (2ull << 32) | (run + total),
                         __ATOMIC_RELEASE, __HIP_MEMORY_SCOPE_AGENT);
      s_base = run;
    }
  }
  __syncthreads();
  unsigned int off = s_base + excl;
#pragma unroll
  for (int j = 0; j < 8; ++j) {
    const int idx = base + j;
    if (idx < L) data[idx] = off;
    off += v[j];
  }
}

// ---------------- scatter: rank -> LDS digit-binning -> coalesced write -------

__global__ __launch_bounds__(256) void scatter_both(
    const ull* __restrict__ sxp, ull* __restrict__ dxp,
    const ull* __restrict__ syp, ull* __restrict__ dyp,
    int* __restrict__ oix, int* __restrict__ oiy,
    const unsigned int* __restrict__ cx, const unsigned int* __restrict__ cy,
    int n, int nbh, int shift) {
  __shared__ ull tile[TILE];                 // 32 KB
  __shared__ unsigned int wh[4 * RADIX];     // 16 KB: per-wave hists -> bases
  __shared__ unsigned int dbase[RADIX];      // 4 KB: globalbase[d]-localstart[d]
  __shared__ unsigned int sscan[256];        // 1 KB
  const int tid = threadIdx.x;
  const int lane = tid & 63;
  const int w = tid >> 6;
  const int logical = xcd_swizzle(blockIdx.x, 2 * nbh);
  const int half = (logical >= nbh) ? 1 : 0;
  const int blk = logical - half * nbh;
  const ull* __restrict__ src = half ? syp : sxp;
  ull* __restrict__ dst = half ? dyp : dxp;
  int* __restrict__ out_idx = half ? oiy : oix;
  const unsigned int* __restrict__ counts = half ? cy : cx;
  const int base = blk * TILE + w * (TILE / 4);  // wave-contiguous 1024-chunks
  const int m = min(TILE, n - blk * TILE);       // valid elements in this block
  for (int d = tid; d < 4 * RADIX; d += 256) wh[d] = 0;
  __syncthreads();
  const ull lt = (1ull << lane) - 1ull;

  // Phase A: load, ballot-rank per wave, per-wave digit histogram
  ull key[TITEMS];
  unsigned int meta[TITEMS];  // d(10) | lr<<10(6) | ldr<<16(6) | cnt<<22(7)
#pragma unroll 4
  for (int j = 0; j < TITEMS; ++j) {
    const int e = base + j * 64 + lane;
    const bool valid = e < n;
    key[j] = valid ? src[e] : 0ull;
    const unsigned int d = (((unsigned int)(key[j] >> 32)) >> shift) & (RADIX - 1);
    ull mm = __ballot(valid);
#pragma unroll
    for (int bbit = 0; bbit < 10; ++bbit) {
      const ull bb = __ballot((d >> bbit) & 1);
      mm &= ((d >> bbit) & 1) ? bb : ~bb;
    }
    const unsigned int lr = (unsigned int)__popcll(mm & lt);
    const unsigned int cnt = (unsigned int)__popcll(mm);
    const unsigned int ldr = mm ? (unsigned int)__builtin_ctzll(mm) : 0u;
    meta[j] = d | (lr << 10) | (ldr << 16) | (cnt << 22);
    if (valid && lr == 0) atomicAdd(&wh[w * RADIX + d], cnt);
  }
  __syncthreads();

  // Phase B: block-wide 1024-bin exclusive scan -> local starts + wave bases
  {
    const int d0 = tid * 4;
    unsigned int c4[4], tsum = 0;
#pragma unroll
    for (int j = 0; j < 4; ++j) {
      const int d = d0 + j;
      unsigned int t = wh[d] + wh[RADIX + d] + wh[2 * RADIX + d] + wh[3 * RADIX + d];
      c4[j] = t;
      tsum += t;
    }
    unsigned int run = block_scan_excl(tsum, sscan);
#pragma unroll
    for (int j = 0; j < 4; ++j) {
      const int d = d0 + j;
      dbase[d] = counts[(size_t)d * nbh + blk] - run;  // pos = dbase[d]+localpos
      unsigned int acc = run;
#pragma unroll
      for (int ww = 0; ww < 4; ++ww) {
        const unsigned int c = wh[ww * RADIX + d];
        wh[ww * RADIX + d] = acc;
        acc += c;
      }
      run += c4[j];
    }
  }
  __syncthreads();

  // Phase C: bin keys into LDS at local positions (stable)
#pragma unroll 4
  for (int j = 0; j < TITEMS; ++j) {
    const bool valid = (base + j * 64 + lane) < n;
    const unsigned int mt = meta[j];
    const unsigned int d = mt & (RADIX - 1);
    const unsigned int lr = (mt >> 10) & 63u;
    const unsigned int ldr = (mt >> 16) & 63u;
    const unsigned int cnt = mt >> 22;
    unsigned int old = 0;
    if (valid && lr == 0) old = atomicAdd(&wh[w * RADIX + d], cnt);
    old = __shfl(old, (int)ldr, 64);
    if (valid) tile[old + lr] = key[j];
  }
  __syncthreads();

  // Phase D: sequential walk -> coalesced global writes
#pragma unroll 4
  for (int j = 0; j < TITEMS; ++j) {
    const int s = j * 256 + tid;
    if (s < m) {
      const ull p = tile[s];
      const unsigned int d = (((unsigned int)(p >> 32)) >> shift) & (RADIX - 1);
      const unsigned int pos = dbase[d] + s;
      if (out_idx) out_idx[pos] = (int)(unsigned int)p;
      else dst[pos] = p;
    }
  }
}

// ---------------- host ----------------

static inline int ceil_div(int a, int b) { return (a + b - 1) / b; }

extern "C" void kernel_launch(void* const* d_in, const int* in_sizes, int n_in,
                              void* d_out, int out_size, void* d_ws, size_t ws_size,
                              hipStream_t stream) {
  const int* coords = (const int*)d_in[0];
  const int* shape = (const int*)d_in[2];
  const int n = in_sizes[0] / 4;
  const int n_p = out_size - 3 * n;

  int* out = (int*)d_out;
  int* flat2win = out;
  int* win2flat = out + n_p;
  int* idx_x = out + (size_t)n_p + n;
  int* idx_y = out + (size_t)n_p + 2 * (size_t)n;

  const int NBH = ceil_div(n, TILE);
  const int NBK = ceil_div((n > n_p) ? n : n_p, TILE);
  const int L = NBH * RADIX;
  const int NS = ceil_div(L, SCAN_CHUNK);

  char* ws = (char*)d_ws;
  size_t off = 0;
  auto take = [&](size_t bytes) -> void* {
    void* p = (void*)(ws + off);
    off += (bytes + 255) & ~(size_t)255;
    return p;
  };
  ull* A = (ull*)take((size_t)n * 8);
  ull* B = (ull*)take((size_t)n * 8);
  ull* C = (ull*)take((size_t)n * 8);
  ull* D = (ull*)take((size_t)n * 8);
  unsigned int* cx0 = (unsigned int*)take((size_t)L * 4);
  unsigned int* cy0 = (unsigned int*)take((size_t)L * 4);
  unsigned int* cx1 = (unsigned int*)take((size_t)L * 4);
  unsigned int* cy1 = (unsigned int*)take((size_t)L * 4);
  ull* desc = (ull*)take((size_t)6 * NS * 8);
  int* bs = (int*)take(128);
  int* bsp = (int*)take(128);
  int* num = (int*)take(64);
  int* nump = (int*)take(64);
  (void)ws_size; (void)n_in;

  hipMemsetAsync(desc, 0, (size_t)6 * NS * 8, stream);
  setup_segments<<<1, 64, 0, stream>>>(coords, n, bs, bsp, num, nump);
  keys_both<<<NBK, 256, 0, stream>>>(coords, shape, bs, bsp, num, nump,
                                     A, C, win2flat, flat2win, cx0, cy0,
                                     n, n_p, NBH);
  // pass 0: A->B, C->D on bits [0,10)
  scan_both<<<2 * NS, 256, 0, stream>>>(cx0, cy0, L, NS, desc + 0 * NS, desc + 1 * NS);
  scatter_both<<<2 * NBH, 256, 0, stream>>>(A, B, C, D, nullptr, nullptr,
                                            cx0, cy0, n, NBH, 0);
  // pass 1: B->A, D->C on bits [10,20)
  hist_both<<<2 * NBH, 256, 0, stream>>>(B, D, cx1, cy1, n, NBH, 10);
  scan_both<<<2 * NS, 256, 0, stream>>>(cx1, cy1, L, NS, desc + 2 * NS, desc + 3 * NS);
  scatter_both<<<2 * NBH, 256, 0, stream>>>(B, A, D, C, nullptr, nullptr,
                                            cx1, cy1, n, NBH, 10);
  // pass 2: A->idx, C->idx on bits [20,30)
  hist_both<<<2 * NBH, 256, 0, stream>>>(A, C, cx0, cy0, n, NBH, 20);
  scan_both<<<2 * NS, 256, 0, stream>>>(cx0, cy0, L, NS, desc + 4 * NS, desc + 5 * NS);
  scatter_both<<<2 * NBH, 256, 0, stream>>>(A, B, C, D, idx_x, idx_y,
                                            cx0, cy0, n, NBH, 20);
}

// Round 9
// 305.294 us; speedup vs baseline: 1.0944x; 1.0944x over previous
//
#include <hip/hip_runtime.h>
#include <stdint.h>
#include <type_traits>

#define NBATCH 16
#define GRP 128
#define RADIX 1024
#define THREADS 768
#define WAVES 12
#define TILE 12288         // 768 threads * 16 items
#define TITEMS 16
#define SCAN_CHUNK 2048
#define IDXMASK 0x1FFFFFu  // n < 2^21 for this problem size

typedef unsigned long long ull;

// XCD-aware swizzle: consecutive logical tiles -> same XCD (round-robin HW map).
__device__ __forceinline__ int xcd_swizzle(int blk, int G) {
  const int x = blk & 7, i = blk >> 3;
  const int q = G >> 3, r = G & 7;
  return x * q + (x < r ? x : r) + i;
}

// ---------------- setup (+ clears scan descriptors) ----------------

__global__ void setup_segments(const int* __restrict__ coords, int n,
                               int* __restrict__ bs, int* __restrict__ bsp,
                               int* __restrict__ num, int* __restrict__ nump,
                               ull* __restrict__ desc, int desc_words) {
  __shared__ int st[NBATCH + 1];
  const int t = threadIdx.x;
  for (int i = t; i < desc_words; i += 256) desc[i] = 0ull;
  if (t <= NBATCH) {
    int lo = 0, hi = n;
    while (lo < hi) {
      const int mid = (lo + hi) >> 1;
      if (coords[4 * mid] < t) lo = mid + 1; else hi = mid;
    }
    st[t] = lo;
  }
  __syncthreads();
  if (t == 0) {
    int b = 0;
    for (int i = 0; i < NBATCH; ++i) {
      const int s = st[i];
      const int ni = st[i + 1] - s;
      bs[i] = s; bsp[i] = b; num[i] = ni;
      const int npi = (ni + GRP - 1) / GRP * GRP;
      nump[i] = npi;
      b += npi;
    }
    bs[NBATCH] = st[NBATCH];
    bsp[NBATCH] = b;
  }
}

// ---------------- keys (both sorts) + w2f + f2w + pass-0 hists ----------------

__global__ __launch_bounds__(THREADS) void keys_both(
    const int* __restrict__ coords, const int* __restrict__ shape,
    const int* __restrict__ bs, const int* __restrict__ bsp,
    const int* __restrict__ num, const int* __restrict__ nump,
    ull* __restrict__ kx, ull* __restrict__ ky,
    int* __restrict__ win2flat, int* __restrict__ f2w,
    unsigned int* __restrict__ cx0, unsigned int* __restrict__ cy0,
    int n, int n_p, int nbh) {
  __shared__ int sbs[NBATCH + 1], sbsp[NBATCH + 1], snum[NBATCH], snump[NBATCH];
  __shared__ unsigned int hx[RADIX], hy[RADIX];
  const int tid = threadIdx.x;
  const int blk = blockIdx.x;
  if (tid <= NBATCH) { sbs[tid] = bs[tid]; sbsp[tid] = bsp[tid]; }
  if (tid < NBATCH) { snum[tid] = num[tid]; snump[tid] = nump[tid]; }
  for (int d = tid; d < RADIX; d += THREADS) { hx[d] = 0; hy[d] = 0; }
  __syncthreads();
  const int sz = shape[0], sy = shape[1], sx = shape[2];
  const int mx = ((sx + 15) >> 4) + 1;
  const int my = ((sy + 15) >> 4) + 1;
  const int mz = ((sz + 7) >> 3) + 1;
  const int mper = mx * my * mz;
  const int base = blk * TILE;
#pragma unroll 4
  for (int j = 0; j < TITEMS; ++j) {
    const int i = base + j * THREADS + tid;
    if (i < n) {
      const int4 c = ((const int4*)coords)[i];
      const int b = c.x, z = c.y, y = c.z, x = c.w;
      const int wcx = x >> 4, cix = x & 15;
      const int wcy = y >> 4, ciy = y & 15;
      const int wcz = z >> 3, ciz = z & 7;
      const int bx = b * mper + wcx * (my * mz) + wcy * mz + wcz;
      const int by = b * mper + wcy * (mx * mz) + wcx * mz + wcz;
      const unsigned int keyx = (unsigned int)(bx * 2048 + cix * 128 + ciy * 8 + ciz);
      const unsigned int keyy = (unsigned int)(by * 2048 + ciy * 128 + cix * 8 + ciz);
      kx[i] = ((ull)keyx << 32) | (unsigned int)i;
      ky[i] = ((ull)keyy << 32) | (unsigned int)i;
      atomicAdd(&hx[keyx & (RADIX - 1)], 1u);
      atomicAdd(&hy[keyy & (RADIX - 1)], 1u);
      win2flat[i] = i + (sbsp[b] - sbs[b]);
    }
    if (i < n_p) {
      const int k = i;
      int b = 0;
#pragma unroll
      for (int jj = 1; jj < NBATCH; ++jj) b += (k >= sbsp[jj]) ? 1 : 0;
      const int bias = sbsp[b] - sbs[b];
      const int nb2 = snum[b], npb = snump[b];
      int val = k - bias;
      if (nb2 != npb && k >= sbsp[b] + nb2) {
        if (npb != GRP) {
          val = k - GRP - bias;
        } else {
          const int m = nb2 > 1 ? nb2 : 1;
          val = sbs[b] + (k - sbsp[b] - nb2) % m;
        }
      }
      f2w[k] = val;
    }
  }
  __syncthreads();
  if (blk < nbh)
    for (int d = tid; d < RADIX; d += THREADS) {
      cx0[(size_t)d * nbh + blk] = hx[d];
      cy0[(size_t)d * nbh + blk] = hy[d];
    }
}

// ---------------- per-block LDS histogram, both sorts ----------------

__global__ __launch_bounds__(THREADS) void hist64(
    const ull* __restrict__ sxp, const ull* __restrict__ syp,
    unsigned int* __restrict__ cx, unsigned int* __restrict__ cy,
    int n, int nbh, int shift) {
  __shared__ unsigned int h[RADIX];
  const int tid = threadIdx.x;
  const int half = (blockIdx.x >= nbh) ? 1 : 0;
  const int blk = blockIdx.x - half * nbh;
  const ull* __restrict__ src = half ? syp : sxp;
  unsigned int* __restrict__ counts = half ? cy : cx;
  for (int d = tid; d < RADIX; d += THREADS) h[d] = 0;
  __syncthreads();
  const int base = blk * TILE;
#pragma unroll 4
  for (int j = 0; j < TITEMS; ++j) {
    const int e = base + j * THREADS + tid;
    if (e < n) {
      const ull p = src[e];
      atomicAdd(&h[(((unsigned int)(p >> 32)) >> shift) & (RADIX - 1)], 1u);
    }
  }
  __syncthreads();
  for (int d = tid; d < RADIX; d += THREADS)
    counts[(size_t)d * nbh + blk] = h[d];
}

__global__ __launch_bounds__(THREADS) void hist32(
    const unsigned int* __restrict__ sxp, const unsigned int* __restrict__ syp,
    unsigned int* __restrict__ cx, unsigned int* __restrict__ cy,
    int n, int nbh) {
  __shared__ unsigned int h[RADIX];
  const int tid = threadIdx.x;
  const int half = (blockIdx.x >= nbh) ? 1 : 0;
  const int blk = blockIdx.x - half * nbh;
  const unsigned int* __restrict__ src = half ? syp : sxp;
  unsigned int* __restrict__ counts = half ? cy : cx;
  for (int d = tid; d < RADIX; d += THREADS) h[d] = 0;
  __syncthreads();
  const int base = blk * TILE;
#pragma unroll 4
  for (int j = 0; j < TITEMS; ++j) {
    const int e = base + j * THREADS + tid;
    if (e < n) atomicAdd(&h[(src[e] >> 21) & (RADIX - 1)], 1u);
  }
  __syncthreads();
  for (int d = tid; d < RADIX; d += THREADS)
    counts[(size_t)d * nbh + blk] = h[d];
}

// ---------------- chained exclusive scan, two independent halves ----------------

__device__ __forceinline__ unsigned int block_scan_excl(unsigned int thread_sum,
                                                        unsigned int* s) {
  const int tid = threadIdx.x;
  s[tid] = thread_sum;
  __syncthreads();
#pragma unroll
  for (int off = 1; off < 256; off <<= 1) {
    unsigned int x = (tid >= off) ? s[tid - off] : 0u;
    __syncthreads();
    s[tid] += x;
    __syncthreads();
  }
  return s[tid] - thread_sum;
}

__global__ void scan_both(unsigned int* __restrict__ cx, unsigned int* __restrict__ cy,
                          int L, int NS, ull* __restrict__ descx,
                          ull* __restrict__ descy) {
  __shared__ unsigned int s[256];
  __shared__ unsigned int s_base;
  const int tid = threadIdx.x;
  const int half = (blockIdx.x >= NS) ? 1 : 0;
  const int blk = blockIdx.x - half * NS;
  unsigned int* data = half ? cy : cx;
  ull* desc = half ? descy : descx;
  const int base = blk * SCAN_CHUNK + tid * 8;
  unsigned int v[8], sum = 0;
#pragma unroll
  for (int j = 0; j < 8; ++j) {
    const int idx = base + j;
    v[j] = (idx < L) ? data[idx] : 0u;
    sum += v[j];
  }
  const unsigned int excl = block_scan_excl(sum, s);
  const unsigned int total = s[255];
  if (tid == 0) {
    const ull tag = (blk == 0) ? (2ull << 32) : (1ull << 32);
    __hip_atomic_store(&desc[blk], tag | total, __ATOMIC_RELEASE,
                       __HIP_MEMORY_SCOPE_AGENT);
    if (blk == 0) s_base = 0;
  }
  if (blk > 0 && tid < 64) {
    unsigned int run = 0;
    int jb = blk - 1;
    for (;;) {
      const int j = jb - tid;
      ull d;
      if (j >= 0) {
        do {
          d = __hip_atomic_load(&desc[j], __ATOMIC_ACQUIRE, __HIP_MEMORY_SCOPE_AGENT);
        } while ((d >> 32) == 0);
      } else {
        d = (2ull << 32);
      }
      const ull m2 = __ballot((d >> 32) == 2);
      const int f = m2 ? __builtin_ctzll(m2) : 64;
      unsigned int contrib = (tid <= f) ? (unsigned int)d : 0u;
#pragma unroll
      for (int o = 32; o > 0; o >>= 1) contrib += __shfl_down(contrib, o, 64);
      run += __shfl(contrib, 0, 64);
      if (m2) break;
      jb -= 64;
    }
    if (tid == 0) {
      __hip_atomic_store(&desc[blk], (2ull << 32) | (run + total),
                         __ATOMIC_RELEASE, __HIP_MEMORY_SCOPE_AGENT);
      s_base = run;
    }
  }
  __syncthreads();
  unsigned int off = s_base + excl;
#pragma unroll
  for (int j = 0; j < 8; ++j) {
    const int idx = base + j;
    if (idx < L) data[idx] = off;
    off += v[j];
  }
}

// ---------------- scatter: 12 waves, register keys, XCD swizzle --------------
// MODE 0: u64 -> u64 (digit bits [shift,shift+10) of key)
// MODE 1: u64 -> packed u32 ((keyhi10<<21)|idx), digit bits [10,20)
// MODE 2: packed u32 -> out_idx, digit = v>>21

template <int MODE>
__global__ __launch_bounds__(THREADS) void scatter_k(
    const void* __restrict__ sxp, void* __restrict__ dxp,
    const void* __restrict__ syp, void* __restrict__ dyp,
    int* __restrict__ oix, int* __restrict__ oiy,
    const unsigned int* __restrict__ cx, const unsigned int* __restrict__ cy,
    int n, int nbh, int shift) {
  using SrcT = typename std::conditional<MODE == 2, unsigned int, ull>::type;
  __shared__ unsigned int wh[WAVES * RADIX];
  const int tid = threadIdx.x;
  const int lane = tid & 63;
  const int w = tid >> 6;
  const int logical = xcd_swizzle(blockIdx.x, 2 * nbh);
  const int half = (logical >= nbh) ? 1 : 0;
  const int blk = logical - half * nbh;
  const SrcT* __restrict__ src = (const SrcT*)(half ? syp : sxp);
  void* __restrict__ dst = half ? dyp : dxp;
  int* __restrict__ out_idx = half ? oiy : oix;
  const unsigned int* __restrict__ counts = half ? cy : cx;
  const int base = blk * TILE + w * (TILE / WAVES);  // wave-contiguous 1024-chunks
  for (int d = tid; d < WAVES * RADIX; d += THREADS) wh[d] = 0;
  __syncthreads();
  const ull lt = (1ull << lane) - 1ull;

  SrcT key[TITEMS];
  unsigned int meta[TITEMS];  // d(10) | lr<<10(6) | ldr<<16(6) | cnt<<22(7)
#pragma unroll 4
  for (int j = 0; j < TITEMS; ++j) {
    const int e = base + j * 64 + lane;
    const bool valid = e < n;
    key[j] = valid ? src[e] : (SrcT)0;
    unsigned int d;
    if (MODE == 2) d = ((unsigned int)key[j] >> 21) & (RADIX - 1);
    else d = (((unsigned int)(((ull)key[j]) >> 32)) >> shift) & (RADIX - 1);
    ull mm = __ballot(valid);
#pragma unroll
    for (int bbit = 0; bbit < 10; ++bbit) {
      const ull bb = __ballot((d >> bbit) & 1);
      mm &= ((d >> bbit) & 1) ? bb : ~bb;
    }
    const unsigned int lr = (unsigned int)__popcll(mm & lt);
    const unsigned int cnt = (unsigned int)__popcll(mm);
    const unsigned int ldr = mm ? (unsigned int)__builtin_ctzll(mm) : 0u;
    meta[j] = d | (lr << 10) | (ldr << 16) | (cnt << 22);
    if (valid && lr == 0) atomicAdd(&wh[w * RADIX + d], cnt);
  }
  __syncthreads();
  // cross-wave prefix + global base
  for (int d = tid; d < RADIX; d += THREADS) {
    unsigned int g = counts[(size_t)d * nbh + blk];
#pragma unroll
    for (int ww = 0; ww < WAVES; ++ww) {
      const unsigned int c = wh[ww * RADIX + d];
      wh[ww * RADIX + d] = g;
      g += c;
    }
  }
  __syncthreads();
#pragma unroll 4
  for (int j = 0; j < TITEMS; ++j) {
    const bool valid = (base + j * 64 + lane) < n;
    const unsigned int mt = meta[j];
    const unsigned int d = mt & (RADIX - 1);
    const unsigned int lr = (mt >> 10) & 63u;
    const unsigned int ldr = (mt >> 16) & 63u;
    const unsigned int cnt = mt >> 22;
    unsigned int old = 0;
    if (valid && lr == 0) old = atomicAdd(&wh[w * RADIX + d], cnt);
    old = __shfl(old, (int)ldr, 64);
    if (valid) {
      const unsigned int pos = old + lr;
      if (MODE == 0) {
        ((ull*)dst)[pos] = (ull)key[j];
      } else if (MODE == 1) {
        const ull k = (ull)key[j];
        ((unsigned int*)dst)[pos] =
            ((unsigned int)((k >> 52) & 1023ull) << 21) | ((unsigned int)k & IDXMASK);
      } else {
        out_idx[pos] = (int)((unsigned int)key[j] & IDXMASK);
      }
    }
  }
}

// ---------------- host ----------------

static inline int ceil_div(int a, int b) { return (a + b - 1) / b; }

extern "C" void kernel_launch(void* const* d_in, const int* in_sizes, int n_in,
                              void* d_out, int out_size, void* d_ws, size_t ws_size,
                              hipStream_t stream) {
  const int* coords = (const int*)d_in[0];
  const int* shape = (const int*)d_in[2];
  const int n = in_sizes[0] / 4;
  const int n_p = out_size - 3 * n;

  int* out = (int*)d_out;
  int* flat2win = out;
  int* win2flat = out + n_p;
  int* idx_x = out + (size_t)n_p + n;
  int* idx_y = out + (size_t)n_p + 2 * (size_t)n;

  const int NBH = ceil_div(n, TILE);
  const int NBK = ceil_div((n > n_p) ? n : n_p, TILE);
  const int L = NBH * RADIX;
  const int NS = ceil_div(L, SCAN_CHUNK);

  char* ws = (char*)d_ws;
  size_t off = 0;
  auto take = [&](size_t bytes) -> void* {
    void* p = (void*)(ws + off);
    off += (bytes + 255) & ~(size_t)255;
    return p;
  };
  ull* A = (ull*)take((size_t)n * 8);
  ull* B = (ull*)take((size_t)n * 8);
  ull* C = (ull*)take((size_t)n * 8);
  ull* D = (ull*)take((size_t)n * 8);
  unsigned int* cx0 = (unsigned int*)take((size_t)L * 4);
  unsigned int* cy0 = (unsigned int*)take((size_t)L * 4);
  unsigned int* cx1 = (unsigned int*)take((size_t)L * 4);
  unsigned int* cy1 = (unsigned int*)take((size_t)L * 4);
  ull* desc = (ull*)take((size_t)6 * NS * 8);
  int* bs = (int*)take(128);
  int* bsp = (int*)take(128);
  int* num = (int*)take(64);
  int* nump = (int*)take(64);
  (void)ws_size; (void)n_in;

  setup_segments<<<1, 256, 0, stream>>>(coords, n, bs, bsp, num, nump,
                                        desc, 6 * NS);
  keys_both<<<NBK, THREADS, 0, stream>>>(coords, shape, bs, bsp, num, nump,
                                         A, C, win2flat, flat2win, cx0, cy0,
                                         n, n_p, NBH);
  // pass 0: bits [0,10): A->B, C->D (u64)
  scan_both<<<2 * NS, 256, 0, stream>>>(cx0, cy0, L, NS, desc + 0 * NS, desc + 1 * NS);
  scatter_k<0><<<2 * NBH, THREADS, 0, stream>>>(A, B, C, D, nullptr, nullptr,
                                                cx0, cy0, n, NBH, 0);
  // pass 1: bits [10,20): B->A(u32 packed), D->C(u32 packed)
  hist64<<<2 * NBH, THREADS, 0, stream>>>(B, D, cx1, cy1, n, NBH, 10);
  scan_both<<<2 * NS, 256, 0, stream>>>(cx1, cy1, L, NS, desc + 2 * NS, desc + 3 * NS);
  scatter_k<1><<<2 * NBH, THREADS, 0, stream>>>(B, A, D, C, nullptr, nullptr,
                                                cx1, cy1, n, NBH, 10);
  // pass 2: bits [20,30) (packed as v>>21): A(u32)->idx_x, C(u32)->idx_y
  hist32<<<2 * NBH, THREADS, 0, stream>>>((unsigned int*)A, (unsigned int*)C,
                                          cx0, cy0, n, NBH);
  scan_both<<<2 * NS, 256, 0, stream>>>(cx0, cy0, L, NS, desc + 4 * NS, desc + 5 * NS);
  scatter_k<2><<<2 * NBH, THREADS, 0, stream>>>(A, B, C, D, idx_x, idx_y,
                                                cx0, cy0, n, NBH, 0);
}

// Round 10
// 296.928 us; speedup vs baseline: 1.1252x; 1.0282x over previous
//
#include <hip/hip_runtime.h>
#include <stdint.h>
#include <type_traits>

#define NBATCH 16
#define GRP 128
#define THREADS 768
#define WAVES 12
#define TILE 12288         // 768 threads * 16 items
#define TITEMS 16
#define SCAN_CHUNK 2048
#define IDXMASK 0x1FFFFFu  // n < 2^21 for this problem size

typedef unsigned long long ull;

// XCD-aware swizzle: consecutive logical tiles -> same XCD (round-robin HW map).
__device__ __forceinline__ int xcd_swizzle(int blk, int G) {
  const int x = blk & 7, i = blk >> 3;
  const int q = G >> 3, r = G & 7;
  return x * q + (x < r ? x : r) + i;
}

// ---------------- setup (+ clears scan descriptors) ----------------

__global__ void setup_segments(const int* __restrict__ coords, int n,
                               int* __restrict__ bs, int* __restrict__ bsp,
                               int* __restrict__ num, int* __restrict__ nump,
                               ull* __restrict__ desc, int desc_words) {
  __shared__ int st[NBATCH + 1];
  const int t = threadIdx.x;
  for (int i = t; i < desc_words; i += 256) desc[i] = 0ull;
  if (t <= NBATCH) {
    int lo = 0, hi = n;
    while (lo < hi) {
      const int mid = (lo + hi) >> 1;
      if (coords[4 * mid] < t) lo = mid + 1; else hi = mid;
    }
    st[t] = lo;
  }
  __syncthreads();
  if (t == 0) {
    int b = 0;
    for (int i = 0; i < NBATCH; ++i) {
      const int s = st[i];
      const int ni = st[i + 1] - s;
      bs[i] = s; bsp[i] = b; num[i] = ni;
      const int npi = (ni + GRP - 1) / GRP * GRP;
      nump[i] = npi;
      b += npi;
    }
    bs[NBATCH] = st[NBATCH];
    bsp[NBATCH] = b;
  }
}

// ---------------- keys (both sorts) + w2f + f2w + pass-0 hists (256 bins) ----

__global__ __launch_bounds__(THREADS) void keys_both(
    const int* __restrict__ coords, const int* __restrict__ shape,
    const int* __restrict__ bs, const int* __restrict__ bsp,
    const int* __restrict__ num, const int* __restrict__ nump,
    ull* __restrict__ kx, ull* __restrict__ ky,
    int* __restrict__ win2flat, int* __restrict__ f2w,
    unsigned int* __restrict__ cx0, unsigned int* __restrict__ cy0,
    int n, int n_p, int nbh) {
  __shared__ int sbs[NBATCH + 1], sbsp[NBATCH + 1], snum[NBATCH], snump[NBATCH];
  __shared__ unsigned int hx[256], hy[256];
  const int tid = threadIdx.x;
  const int blk = blockIdx.x;
  if (tid <= NBATCH) { sbs[tid] = bs[tid]; sbsp[tid] = bsp[tid]; }
  if (tid < NBATCH) { snum[tid] = num[tid]; snump[tid] = nump[tid]; }
  if (tid < 256) { hx[tid] = 0; hy[tid] = 0; }
  __syncthreads();
  const int sz = shape[0], sy = shape[1], sx = shape[2];
  const int mx = ((sx + 15) >> 4) + 1;
  const int my = ((sy + 15) >> 4) + 1;
  const int mz = ((sz + 7) >> 3) + 1;
  const int mper = mx * my * mz;
  const int base = blk * TILE;
#pragma unroll 4
  for (int j = 0; j < TITEMS; ++j) {
    const int i = base + j * THREADS + tid;
    if (i < n) {
      const int4 c = ((const int4*)coords)[i];
      const int b = c.x, z = c.y, y = c.z, x = c.w;
      const int wcx = x >> 4, cix = x & 15;
      const int wcy = y >> 4, ciy = y & 15;
      const int wcz = z >> 3, ciz = z & 7;
      const int bx = b * mper + wcx * (my * mz) + wcy * mz + wcz;
      const int by = b * mper + wcy * (mx * mz) + wcx * mz + wcz;
      const unsigned int keyx = (unsigned int)(bx * 2048 + cix * 128 + ciy * 8 + ciz);
      const unsigned int keyy = (unsigned int)(by * 2048 + ciy * 128 + cix * 8 + ciz);
      kx[i] = ((ull)keyx << 32) | (unsigned int)i;
      ky[i] = ((ull)keyy << 32) | (unsigned int)i;
      atomicAdd(&hx[keyx & 255], 1u);
      atomicAdd(&hy[keyy & 255], 1u);
      win2flat[i] = i + (sbsp[b] - sbs[b]);
    }
    if (i < n_p) {
      const int k = i;
      int b = 0;
#pragma unroll
      for (int jj = 1; jj < NBATCH; ++jj) b += (k >= sbsp[jj]) ? 1 : 0;
      const int bias = sbsp[b] - sbs[b];
      const int nb2 = snum[b], npb = snump[b];
      int val = k - bias;
      if (nb2 != npb && k >= sbsp[b] + nb2) {
        if (npb != GRP) {
          val = k - GRP - bias;
        } else {
          const int m = nb2 > 1 ? nb2 : 1;
          val = sbs[b] + (k - sbsp[b] - nb2) % m;
        }
      }
      f2w[k] = val;
    }
  }
  __syncthreads();
  if (blk < nbh && tid < 256) {
    cx0[(size_t)tid * nbh + blk] = hx[tid];
    cy0[(size_t)tid * nbh + blk] = hy[tid];
  }
}

// ---------------- per-block LDS histograms ----------------

__global__ __launch_bounds__(THREADS) void hist64(
    const ull* __restrict__ sxp, const ull* __restrict__ syp,
    unsigned int* __restrict__ cx, unsigned int* __restrict__ cy,
    int n, int nbh, int shift) {
  __shared__ unsigned int h[256];
  const int tid = threadIdx.x;
  const int half = (blockIdx.x >= nbh) ? 1 : 0;
  const int blk = blockIdx.x - half * nbh;
  const ull* __restrict__ src = half ? syp : sxp;
  unsigned int* __restrict__ counts = half ? cy : cx;
  if (tid < 256) h[tid] = 0;
  __syncthreads();
  const int base = blk * TILE;
#pragma unroll 4
  for (int j = 0; j < TITEMS; ++j) {
    const int e = base + j * THREADS + tid;
    if (e < n) {
      const ull p = src[e];
      atomicAdd(&h[(((unsigned int)(p >> 32)) >> shift) & 255], 1u);
    }
  }
  __syncthreads();
  if (tid < 256) counts[(size_t)tid * nbh + blk] = h[tid];
}

__global__ __launch_bounds__(THREADS) void hist32(
    const unsigned int* __restrict__ sxp, const unsigned int* __restrict__ syp,
    unsigned int* __restrict__ cx, unsigned int* __restrict__ cy,
    int n, int nbh) {
  __shared__ unsigned int h[64];
  const int tid = threadIdx.x;
  const int half = (blockIdx.x >= nbh) ? 1 : 0;
  const int blk = blockIdx.x - half * nbh;
  const unsigned int* __restrict__ src = half ? syp : sxp;
  unsigned int* __restrict__ counts = half ? cy : cx;
  if (tid < 64) h[tid] = 0;
  __syncthreads();
  const int base = blk * TILE;
#pragma unroll 4
  for (int j = 0; j < TITEMS; ++j) {
    const int e = base + j * THREADS + tid;
    if (e < n) atomicAdd(&h[src[e] >> 21], 1u);
  }
  __syncthreads();
  if (tid < 64) counts[(size_t)tid * nbh + blk] = h[tid];
}

// ---------------- chained exclusive scan, two independent halves ----------------

__device__ __forceinline__ unsigned int block_scan_excl(unsigned int thread_sum,
                                                        unsigned int* s) {
  const int tid = threadIdx.x;
  s[tid] = thread_sum;
  __syncthreads();
#pragma unroll
  for (int off = 1; off < 256; off <<= 1) {
    unsigned int x = (tid >= off) ? s[tid - off] : 0u;
    __syncthreads();
    s[tid] += x;
    __syncthreads();
  }
  return s[tid] - thread_sum;
}

__global__ void scan_both(unsigned int* __restrict__ cx, unsigned int* __restrict__ cy,
                          int L, int NS, ull* __restrict__ descx,
                          ull* __restrict__ descy) {
  __shared__ unsigned int s[256];
  __shared__ unsigned int s_base;
  const int tid = threadIdx.x;
  const int half = (blockIdx.x >= NS) ? 1 : 0;
  const int blk = blockIdx.x - half * NS;
  unsigned int* data = half ? cy : cx;
  ull* desc = half ? descy : descx;
  const int base = blk * SCAN_CHUNK + tid * 8;
  unsigned int v[8], sum = 0;
#pragma unroll
  for (int j = 0; j < 8; ++j) {
    const int idx = base + j;
    v[j] = (idx < L) ? data[idx] : 0u;
    sum += v[j];
  }
  const unsigned int excl = block_scan_excl(sum, s);
  const unsigned int total = s[255];
  if (tid == 0) {
    const ull tag = (blk == 0) ? (2ull << 32) : (1ull << 32);
    __hip_atomic_store(&desc[blk], tag | total, __ATOMIC_RELEASE,
                       __HIP_MEMORY_SCOPE_AGENT);
    if (blk == 0) s_base = 0;
  }
  if (blk > 0 && tid < 64) {
    unsigned int run = 0;
    int jb = blk - 1;
    for (;;) {
      const int j = jb - tid;
      ull d;
      if (j >= 0) {
        do {
          d = __hip_atomic_load(&desc[j], __ATOMIC_ACQUIRE, __HIP_MEMORY_SCOPE_AGENT);
        } while ((d >> 32) == 0);
      } else {
        d = (2ull << 32);
      }
      const ull m2 = __ballot((d >> 32) == 2);
      const int f = m2 ? __builtin_ctzll(m2) : 64;
      unsigned int contrib = (tid <= f) ? (unsigned int)d : 0u;
#pragma unroll
      for (int o = 32; o > 0; o >>= 1) contrib += __shfl_down(contrib, o, 64);
      run += __shfl(contrib, 0, 64);
      if (m2) break;
      jb -= 64;
    }
    if (tid == 0) {
      __hip_atomic_store(&desc[blk], (2ull << 32) | (run + total),
                         __ATOMIC_RELEASE, __HIP_MEMORY_SCOPE_AGENT);
      s_base = run;
    }
  }
  __syncthreads();
  unsigned int off = s_base + excl;
#pragma unroll
  for (int j = 0; j < 8; ++j) {
    const int idx = base + j;
    if (idx < L) data[idx] = off;
    off += v[j];
  }
}

// ---------------- scatter: 8-bit digits, register keys, XCD swizzle ----------
// MODE 0: u64 -> u64, digit bits [shift,shift+8) of hi key
// MODE 1: u64 -> packed u32 ((keyhi6<<21)|idx), digit bits [16,24)
// MODE 2: packed u32 -> out_idx, digit = v>>21 (64 bins)

template <int MODE>
__global__ __launch_bounds__(THREADS) void scatter_k(
    const void* __restrict__ sxp, void* __restrict__ dxp,
    const void* __restrict__ syp, void* __restrict__ dyp,
    int* __restrict__ oix, int* __restrict__ oiy,
    const unsigned int* __restrict__ cx, const unsigned int* __restrict__ cy,
    int n, int nbh, int shift) {
  using SrcT = typename std::conditional<MODE == 2, unsigned int, ull>::type;
  constexpr int R = (MODE == 2) ? 64 : 256;
  constexpr int BITS = (MODE == 2) ? 6 : 8;
  __shared__ unsigned int wh[WAVES * R];
  const int tid = threadIdx.x;
  const int lane = tid & 63;
  const int w = tid >> 6;
  const int logical = xcd_swizzle(blockIdx.x, 2 * nbh);
  const int half = (logical >= nbh) ? 1 : 0;
  const int blk = logical - half * nbh;
  const SrcT* __restrict__ src = (const SrcT*)(half ? syp : sxp);
  void* __restrict__ dst = half ? dyp : dxp;
  int* __restrict__ out_idx = half ? oiy : oix;
  const unsigned int* __restrict__ counts = half ? cy : cx;
  const int base = blk * TILE + w * (TILE / WAVES);  // wave-contiguous 1024-chunks
  for (int d = tid; d < WAVES * R; d += THREADS) wh[d] = 0;
  __syncthreads();
  const ull lt = (1ull << lane) - 1ull;

  SrcT key[TITEMS];
  unsigned int meta[TITEMS];  // d(8) | lr<<8(6) | ldr<<14(6) | cnt<<20(7)
#pragma unroll 4
  for (int j = 0; j < TITEMS; ++j) {
    const int e = base + j * 64 + lane;
    const bool valid = e < n;
    key[j] = valid ? src[e] : (SrcT)0;
    unsigned int d;
    if (MODE == 2) d = (unsigned int)key[j] >> 21;
    else d = (((unsigned int)(((ull)key[j]) >> 32)) >> shift) & 255u;
    ull mm = __ballot(valid);
#pragma unroll
    for (int bbit = 0; bbit < BITS; ++bbit) {
      const ull bb = __ballot((d >> bbit) & 1);
      mm &= ((d >> bbit) & 1) ? bb : ~bb;
    }
    const unsigned int lr = (unsigned int)__popcll(mm & lt);
    const unsigned int cnt = (unsigned int)__popcll(mm);
    const unsigned int ldr = mm ? (unsigned int)__builtin_ctzll(mm) : 0u;
    meta[j] = d | (lr << 8) | (ldr << 14) | (cnt << 20);
    if (valid && lr == 0) atomicAdd(&wh[w * R + d], cnt);
  }
  __syncthreads();
  // cross-wave prefix + global base
  for (int d = tid; d < R; d += THREADS) {
    unsigned int g = counts[(size_t)d * nbh + blk];
#pragma unroll
    for (int ww = 0; ww < WAVES; ++ww) {
      const unsigned int c = wh[ww * R + d];
      wh[ww * R + d] = g;
      g += c;
    }
  }
  __syncthreads();
#pragma unroll 4
  for (int j = 0; j < TITEMS; ++j) {
    const bool valid = (base + j * 64 + lane) < n;
    const unsigned int mt = meta[j];
    const unsigned int d = mt & 255u;
    const unsigned int lr = (mt >> 8) & 63u;
    const unsigned int ldr = (mt >> 14) & 63u;
    const unsigned int cnt = mt >> 20;
    unsigned int old = 0;
    if (valid && lr == 0) old = atomicAdd(&wh[w * R + d], cnt);
    old = __shfl(old, (int)ldr, 64);
    if (valid) {
      const unsigned int pos = old + lr;
      if (MODE == 0) {
        ((ull*)dst)[pos] = (ull)key[j];
      } else if (MODE == 1) {
        const ull k = (ull)key[j];
        ((unsigned int*)dst)[pos] =
            ((unsigned int)((k >> 56) & 63ull) << 21) | ((unsigned int)k & IDXMASK);
      } else {
        out_idx[pos] = (int)((unsigned int)key[j] & IDXMASK);
      }
    }
  }
}

// ---------------- host ----------------

static inline int ceil_div(int a, int b) { return (a + b - 1) / b; }

extern "C" void kernel_launch(void* const* d_in, const int* in_sizes, int n_in,
                              void* d_out, int out_size, void* d_ws, size_t ws_size,
                              hipStream_t stream) {
  const int* coords = (const int*)d_in[0];
  const int* shape = (const int*)d_in[2];
  const int n = in_sizes[0] / 4;
  const int n_p = out_size - 3 * n;

  int* out = (int*)d_out;
  int* flat2win = out;
  int* win2flat = out + n_p;
  int* idx_x = out + (size_t)n_p + n;
  int* idx_y = out + (size_t)n_p + 2 * (size_t)n;

  const int NBH = ceil_div(n, TILE);
  const int NBK = ceil_div((n > n_p) ? n : n_p, TILE);
  const int L8 = NBH * 256;               // 8-bit passes
  const int L6 = NBH * 64;                // 6-bit pass
  const int NS8 = ceil_div(L8, SCAN_CHUNK);
  const int NS6 = ceil_div(L6, SCAN_CHUNK);

  char* ws = (char*)d_ws;
  size_t off = 0;
  auto take = [&](size_t bytes) -> void* {
    void* p = (void*)(ws + off);
    off += (bytes + 255) & ~(size_t)255;
    return p;
  };
  ull* A = (ull*)take((size_t)n * 8);
  ull* B = (ull*)take((size_t)n * 8);
  ull* C = (ull*)take((size_t)n * 8);
  ull* D = (ull*)take((size_t)n * 8);
  unsigned int* cx0 = (unsigned int*)take((size_t)L8 * 4);
  unsigned int* cy0 = (unsigned int*)take((size_t)L8 * 4);
  unsigned int* cx1 = (unsigned int*)take((size_t)L8 * 4);
  unsigned int* cy1 = (unsigned int*)take((size_t)L8 * 4);
  ull* desc = (ull*)take((size_t)8 * NS8 * 8);
  int* bs = (int*)take(128);
  int* bsp = (int*)take(128);
  int* num = (int*)take(64);
  int* nump = (int*)take(64);
  (void)ws_size; (void)n_in;

  setup_segments<<<1, 256, 0, stream>>>(coords, n, bs, bsp, num, nump,
                                        desc, 8 * NS8);
  keys_both<<<NBK, THREADS, 0, stream>>>(coords, shape, bs, bsp, num, nump,
                                         A, C, win2flat, flat2win, cx0, cy0,
                                         n, n_p, NBH);
  // pass 0: bits [0,8): A->B, C->D (u64)
  scan_both<<<2 * NS8, 256, 0, stream>>>(cx0, cy0, L8, NS8, desc + 0 * NS8,
                                         desc + 1 * NS8);
  scatter_k<0><<<2 * NBH, THREADS, 0, stream>>>(A, B, C, D, nullptr, nullptr,
                                                cx0, cy0, n, NBH, 0);
  // pass 1: bits [8,16): B->A, D->C (u64)
  hist64<<<2 * NBH, THREADS, 0, stream>>>(B, D, cx1, cy1, n, NBH, 8);
  scan_both<<<2 * NS8, 256, 0, stream>>>(cx1, cy1, L8, NS8, desc + 2 * NS8,
                                         desc + 3 * NS8);
  scatter_k<0><<<2 * NBH, THREADS, 0, stream>>>(B, A, D, C, nullptr, nullptr,
                                                cx1, cy1, n, NBH, 8);
  // pass 2: bits [16,24): A->B(u32 packed), C->D(u32 packed)
  hist64<<<2 * NBH, THREADS, 0, stream>>>(A, C, cx0, cy0, n, NBH, 16);
  scan_both<<<2 * NS8, 256, 0, stream>>>(cx0, cy0, L8, NS8, desc + 4 * NS8,
                                         desc + 5 * NS8);
  scatter_k<1><<<2 * NBH, THREADS, 0, stream>>>(A, B, C, D, nullptr, nullptr,
                                                cx0, cy0, n, NBH, 16);
  // pass 3: bits [24,30) (packed as v>>21): B(u32)->idx_x, D(u32)->idx_y
  hist32<<<2 * NBH, THREADS, 0, stream>>>((unsigned int*)B, (unsigned int*)D,
                                          cx1, cy1, n, NBH);
  scan_both<<<2 * NS6, 256, 0, stream>>>(cx1, cy1, L6, NS6, desc + 6 * NS8,
                                         desc + 7 * NS8);
  scatter_k<2><<<2 * NBH, THREADS, 0, stream>>>(B, A, D, C, idx_x, idx_y,
                                                cx1, cy1, n, NBH, 0);
}

// Round 11
// 249.057 us; speedup vs baseline: 1.3415x; 1.1922x over previous
//
#include <hip/hip_runtime.h>
#include <stdint.h>
#include <type_traits>

#define NBATCH 16
#define GRP 128
#define THREADS 512
#define WAVES 8
#define TILE 4096          // 512 threads * 8 items
#define TITEMS 8
#define SCAN_CHUNK 2048
#define IDXMASK 0x1FFFFFu  // n < 2^21 for this problem size

typedef unsigned long long ull;

// XCD-aware swizzle: consecutive logical tiles -> same XCD (round-robin HW map).
__device__ __forceinline__ int xcd_swizzle(int blk, int G) {
  const int x = blk & 7, i = blk >> 3;
  const int q = G >> 3, r = G & 7;
  return x * q + (x < r ? x : r) + i;
}

// ---------------- setup (+ clears scan descriptors) ----------------

__global__ void setup_segments(const int* __restrict__ coords, int n,
                               int* __restrict__ bs, int* __restrict__ bsp,
                               int* __restrict__ num, int* __restrict__ nump,
                               ull* __restrict__ desc, int desc_words) {
  __shared__ int st[NBATCH + 1];
  const int t = threadIdx.x;
  for (int i = t; i < desc_words; i += 256) desc[i] = 0ull;
  if (t <= NBATCH) {
    int lo = 0, hi = n;
    while (lo < hi) {
      const int mid = (lo + hi) >> 1;
      if (coords[4 * mid] < t) lo = mid + 1; else hi = mid;
    }
    st[t] = lo;
  }
  __syncthreads();
  if (t == 0) {
    int b = 0;
    for (int i = 0; i < NBATCH; ++i) {
      const int s = st[i];
      const int ni = st[i + 1] - s;
      bs[i] = s; bsp[i] = b; num[i] = ni;
      const int npi = (ni + GRP - 1) / GRP * GRP;
      nump[i] = npi;
      b += npi;
    }
    bs[NBATCH] = st[NBATCH];
    bsp[NBATCH] = b;
  }
}

// ---------------- keys (both sorts) + w2f + f2w + pass-0 hists (256 bins) ----

__global__ __launch_bounds__(THREADS) void keys_both(
    const int* __restrict__ coords, const int* __restrict__ shape,
    const int* __restrict__ bs, const int* __restrict__ bsp,
    const int* __restrict__ num, const int* __restrict__ nump,
    ull* __restrict__ kx, ull* __restrict__ ky,
    int* __restrict__ win2flat, int* __restrict__ f2w,
    unsigned int* __restrict__ cx0, unsigned int* __restrict__ cy0,
    int n, int n_p, int nbh) {
  __shared__ int sbs[NBATCH + 1], sbsp[NBATCH + 1], snum[NBATCH], snump[NBATCH];
  __shared__ unsigned int hx[256], hy[256];
  const int tid = threadIdx.x;
  const int blk = blockIdx.x;
  if (tid <= NBATCH) { sbs[tid] = bs[tid]; sbsp[tid] = bsp[tid]; }
  if (tid < NBATCH) { snum[tid] = num[tid]; snump[tid] = nump[tid]; }
  if (tid < 256) { hx[tid] = 0; hy[tid] = 0; }
  __syncthreads();
  const int sz = shape[0], sy = shape[1], sx = shape[2];
  const int mx = ((sx + 15) >> 4) + 1;
  const int my = ((sy + 15) >> 4) + 1;
  const int mz = ((sz + 7) >> 3) + 1;
  const int mper = mx * my * mz;
  const int base = blk * TILE;
#pragma unroll 4
  for (int j = 0; j < TITEMS; ++j) {
    const int i = base + j * THREADS + tid;
    if (i < n) {
      const int4 c = ((const int4*)coords)[i];
      const int b = c.x, z = c.y, y = c.z, x = c.w;
      const int wcx = x >> 4, cix = x & 15;
      const int wcy = y >> 4, ciy = y & 15;
      const int wcz = z >> 3, ciz = z & 7;
      const int bx = b * mper + wcx * (my * mz) + wcy * mz + wcz;
      const int by = b * mper + wcy * (mx * mz) + wcx * mz + wcz;
      const unsigned int keyx = (unsigned int)(bx * 2048 + cix * 128 + ciy * 8 + ciz);
      const unsigned int keyy = (unsigned int)(by * 2048 + ciy * 128 + cix * 8 + ciz);
      kx[i] = ((ull)keyx << 32) | (unsigned int)i;
      ky[i] = ((ull)keyy << 32) | (unsigned int)i;
      atomicAdd(&hx[keyx & 255], 1u);
      atomicAdd(&hy[keyy & 255], 1u);
      win2flat[i] = i + (sbsp[b] - sbs[b]);
    }
    if (i < n_p) {
      const int k = i;
      int b = 0;
#pragma unroll
      for (int jj = 1; jj < NBATCH; ++jj) b += (k >= sbsp[jj]) ? 1 : 0;
      const int bias = sbsp[b] - sbs[b];
      const int nb2 = snum[b], npb = snump[b];
      int val = k - bias;
      if (nb2 != npb && k >= sbsp[b] + nb2) {
        if (npb != GRP) {
          val = k - GRP - bias;
        } else {
          const int m = nb2 > 1 ? nb2 : 1;
          val = sbs[b] + (k - sbsp[b] - nb2) % m;
        }
      }
      f2w[k] = val;
    }
  }
  __syncthreads();
  if (blk < nbh && tid < 256) {
    cx0[(size_t)tid * nbh + blk] = hx[tid];
    cy0[(size_t)tid * nbh + blk] = hy[tid];
  }
}

// ---------------- per-block LDS histograms ----------------

__global__ __launch_bounds__(THREADS) void hist64(
    const ull* __restrict__ sxp, const ull* __restrict__ syp,
    unsigned int* __restrict__ cx, unsigned int* __restrict__ cy,
    int n, int nbh, int shift) {
  __shared__ unsigned int h[256];
  const int tid = threadIdx.x;
  const int half = (blockIdx.x >= nbh) ? 1 : 0;
  const int blk = blockIdx.x - half * nbh;
  const ull* __restrict__ src = half ? syp : sxp;
  unsigned int* __restrict__ counts = half ? cy : cx;
  if (tid < 256) h[tid] = 0;
  __syncthreads();
  const int base = blk * TILE;
#pragma unroll 4
  for (int j = 0; j < TITEMS; ++j) {
    const int e = base + j * THREADS + tid;
    if (e < n) {
      const ull p = src[e];
      atomicAdd(&h[(((unsigned int)(p >> 32)) >> shift) & 255], 1u);
    }
  }
  __syncthreads();
  if (tid < 256) counts[(size_t)tid * nbh + blk] = h[tid];
}

__global__ __launch_bounds__(THREADS) void hist32(
    const unsigned int* __restrict__ sxp, const unsigned int* __restrict__ syp,
    unsigned int* __restrict__ cx, unsigned int* __restrict__ cy,
    int n, int nbh) {
  __shared__ unsigned int h[64];
  const int tid = threadIdx.x;
  const int half = (blockIdx.x >= nbh) ? 1 : 0;
  const int blk = blockIdx.x - half * nbh;
  const unsigned int* __restrict__ src = half ? syp : sxp;
  unsigned int* __restrict__ counts = half ? cy : cx;
  if (tid < 64) h[tid] = 0;
  __syncthreads();
  const int base = blk * TILE;
#pragma unroll 4
  for (int j = 0; j < TITEMS; ++j) {
    const int e = base + j * THREADS + tid;
    if (e < n) atomicAdd(&h[src[e] >> 21], 1u);
  }
  __syncthreads();
  if (tid < 64) counts[(size_t)tid * nbh + blk] = h[tid];
}

// ---------------- chained exclusive scan, two independent halves ----------------

__device__ __forceinline__ unsigned int block_scan_excl(unsigned int thread_sum,
                                                        unsigned int* s) {
  const int tid = threadIdx.x;
  s[tid] = thread_sum;
  __syncthreads();
#pragma unroll
  for (int off = 1; off < 256; off <<= 1) {
    unsigned int x = (tid >= off) ? s[tid - off] : 0u;
    __syncthreads();
    s[tid] += x;
    __syncthreads();
  }
  return s[tid] - thread_sum;
}

__global__ void scan_both(unsigned int* __restrict__ cx, unsigned int* __restrict__ cy,
                          int L, int NS, ull* __restrict__ descx,
                          ull* __restrict__ descy) {
  __shared__ unsigned int s[256];
  __shared__ unsigned int s_base;
  const int tid = threadIdx.x;
  const int half = (blockIdx.x >= NS) ? 1 : 0;
  const int blk = blockIdx.x - half * NS;
  unsigned int* data = half ? cy : cx;
  ull* desc = half ? descy : descx;
  const int base = blk * SCAN_CHUNK + tid * 8;
  unsigned int v[8], sum = 0;
#pragma unroll
  for (int j = 0; j < 8; ++j) {
    const int idx = base + j;
    v[j] = (idx < L) ? data[idx] : 0u;
    sum += v[j];
  }
  const unsigned int excl = block_scan_excl(sum, s);
  const unsigned int total = s[255];
  if (tid == 0) {
    const ull tag = (blk == 0) ? (2ull << 32) : (1ull << 32);
    __hip_atomic_store(&desc[blk], tag | total, __ATOMIC_RELEASE,
                       __HIP_MEMORY_SCOPE_AGENT);
    if (blk == 0) s_base = 0;
  }
  if (blk > 0 && tid < 64) {
    unsigned int run = 0;
    int jb = blk - 1;
    for (;;) {
      const int j = jb - tid;
      ull d;
      if (j >= 0) {
        do {
          d = __hip_atomic_load(&desc[j], __ATOMIC_ACQUIRE, __HIP_MEMORY_SCOPE_AGENT);
        } while ((d >> 32) == 0);
      } else {
        d = (2ull << 32);
      }
      const ull m2 = __ballot((d >> 32) == 2);
      const int f = m2 ? __builtin_ctzll(m2) : 64;
      unsigned int contrib = (tid <= f) ? (unsigned int)d : 0u;
#pragma unroll
      for (int o = 32; o > 0; o >>= 1) contrib += __shfl_down(contrib, o, 64);
      run += __shfl(contrib, 0, 64);
      if (m2) break;
      jb -= 64;
    }
    if (tid == 0) {
      __hip_atomic_store(&desc[blk], (2ull << 32) | (run + total),
                         __ATOMIC_RELEASE, __HIP_MEMORY_SCOPE_AGENT);
      s_base = run;
    }
  }
  __syncthreads();
  unsigned int off = s_base + excl;
#pragma unroll
  for (int j = 0; j < 8; ++j) {
    const int idx = base + j;
    if (idx < L) data[idx] = off;
    off += v[j];
  }
}

// ---------------- scatter: 8-bit digits, single rank phase, XCD swizzle ------
// MODE 0: u64 -> u64, digit bits [shift,shift+8) of hi key
// MODE 1: u64 -> packed u32 ((keyhi6<<21)|idx), digit bits [16,24)
// MODE 2: packed u32 -> out_idx, digit = v>>21 (64 bins)

template <int MODE>
__global__ __launch_bounds__(THREADS) void scatter_k(
    const void* __restrict__ sxp, void* __restrict__ dxp,
    const void* __restrict__ syp, void* __restrict__ dyp,
    int* __restrict__ oix, int* __restrict__ oiy,
    const unsigned int* __restrict__ cx, const unsigned int* __restrict__ cy,
    int n, int nbh, int shift) {
  using SrcT = typename std::conditional<MODE == 2, unsigned int, ull>::type;
  constexpr int R = (MODE == 2) ? 64 : 256;
  constexpr int BITS = (MODE == 2) ? 6 : 8;
  __shared__ unsigned int wh[WAVES * R];
  const int tid = threadIdx.x;
  const int lane = tid & 63;
  const int w = tid >> 6;
  const int logical = xcd_swizzle(blockIdx.x, 2 * nbh);
  const int half = (logical >= nbh) ? 1 : 0;
  const int blk = logical - half * nbh;
  const SrcT* __restrict__ src = (const SrcT*)(half ? syp : sxp);
  void* __restrict__ dst = half ? dyp : dxp;
  int* __restrict__ out_idx = half ? oiy : oix;
  const unsigned int* __restrict__ counts = half ? cy : cx;
  const int base = blk * TILE + w * (TILE / WAVES);  // wave-contiguous 512-chunks
  for (int d = tid; d < WAVES * R; d += THREADS) wh[d] = 0;
  __syncthreads();
  const ull lt = (1ull << lane) - 1ull;

  // Phase A: load + ballot-rank; leader's LDS atomic return gives the stable
  // wave-local running offset -> wloc. meta = d | (wloc << 8).
  SrcT key[TITEMS];
  unsigned int meta[TITEMS];
#pragma unroll
  for (int j = 0; j < TITEMS; ++j) {
    const int e = base + j * 64 + lane;
    const bool valid = e < n;
    key[j] = valid ? src[e] : (SrcT)0;
    unsigned int d;
    if (MODE == 2) d = (unsigned int)key[j] >> 21;
    else d = (((unsigned int)(((ull)key[j]) >> 32)) >> shift) & 255u;
    ull mm = __ballot(valid);
#pragma unroll
    for (int bbit = 0; bbit < BITS; ++bbit) {
      const ull bb = __ballot((d >> bbit) & 1);
      mm &= ((d >> bbit) & 1) ? bb : ~bb;
    }
    const unsigned int lr = (unsigned int)__popcll(mm & lt);
    const unsigned int cnt = (unsigned int)__popcll(mm);
    const int ldr = mm ? (int)__builtin_ctzll(mm) : 0;
    unsigned int old = 0;
    if (valid && lr == 0) old = atomicAdd(&wh[w * R + d], cnt);
    old = __shfl(old, ldr, 64);
    meta[j] = d | ((old + lr) << 8);
  }
  __syncthreads();
  // Phase B: cross-wave prefix + global base (wh rows become absolute bases)
  for (int d = tid; d < R; d += THREADS) {
    unsigned int g = counts[(size_t)d * nbh + blk];
#pragma unroll
    for (int ww = 0; ww < WAVES; ++ww) {
      const unsigned int c = wh[ww * R + d];
      wh[ww * R + d] = g;
      g += c;
    }
  }
  __syncthreads();
  // Phase C: pure compute + store (LDS read is same-address broadcast per digit)
#pragma unroll
  for (int j = 0; j < TITEMS; ++j) {
    const bool valid = (base + j * 64 + lane) < n;
    const unsigned int mt = meta[j];
    const unsigned int d = mt & 255u;
    const unsigned int pos = wh[w * R + d] + (mt >> 8);
    if (valid) {
      if (MODE == 0) {
        ((ull*)dst)[pos] = (ull)key[j];
      } else if (MODE == 1) {
        const ull k = (ull)key[j];
        ((unsigned int*)dst)[pos] =
            ((unsigned int)((k >> 56) & 63ull) << 21) | ((unsigned int)k & IDXMASK);
      } else {
        out_idx[pos] = (int)((unsigned int)key[j] & IDXMASK);
      }
    }
  }
}

// ---------------- host ----------------

static inline int ceil_div(int a, int b) { return (a + b - 1) / b; }

extern "C" void kernel_launch(void* const* d_in, const int* in_sizes, int n_in,
                              void* d_out, int out_size, void* d_ws, size_t ws_size,
                              hipStream_t stream) {
  const int* coords = (const int*)d_in[0];
  const int* shape = (const int*)d_in[2];
  const int n = in_sizes[0] / 4;
  const int n_p = out_size - 3 * n;

  int* out = (int*)d_out;
  int* flat2win = out;
  int* win2flat = out + n_p;
  int* idx_x = out + (size_t)n_p + n;
  int* idx_y = out + (size_t)n_p + 2 * (size_t)n;

  const int NBH = ceil_div(n, TILE);
  const int NBK = ceil_div((n > n_p) ? n : n_p, TILE);
  const int L8 = NBH * 256;
  const int L6 = NBH * 64;
  const int NS8 = ceil_div(L8, SCAN_CHUNK);
  const int NS6 = ceil_div(L6, SCAN_CHUNK);

  char* ws = (char*)d_ws;
  size_t off = 0;
  auto take = [&](size_t bytes) -> void* {
    void* p = (void*)(ws + off);
    off += (bytes + 255) & ~(size_t)255;
    return p;
  };
  ull* A = (ull*)take((size_t)n * 8);
  ull* B = (ull*)take((size_t)n * 8);
  ull* C = (ull*)take((size_t)n * 8);
  ull* D = (ull*)take((size_t)n * 8);
  unsigned int* cx0 = (unsigned int*)take((size_t)L8 * 4);
  unsigned int* cy0 = (unsigned int*)take((size_t)L8 * 4);
  unsigned int* cx1 = (unsigned int*)take((size_t)L8 * 4);
  unsigned int* cy1 = (unsigned int*)take((size_t)L8 * 4);
  ull* desc = (ull*)take((size_t)8 * NS8 * 8);
  int* bs = (int*)take(128);
  int* bsp = (int*)take(128);
  int* num = (int*)take(64);
  int* nump = (int*)take(64);
  (void)ws_size; (void)n_in;

  setup_segments<<<1, 256, 0, stream>>>(coords, n, bs, bsp, num, nump,
                                        desc, 8 * NS8);
  keys_both<<<NBK, THREADS, 0, stream>>>(coords, shape, bs, bsp, num, nump,
                                         A, C, win2flat, flat2win, cx0, cy0,
                                         n, n_p, NBH);
  // pass 0: bits [0,8): A->B, C->D (u64)
  scan_both<<<2 * NS8, 256, 0, stream>>>(cx0, cy0, L8, NS8, desc + 0 * NS8,
                                         desc + 1 * NS8);
  scatter_k<0><<<2 * NBH, THREADS, 0, stream>>>(A, B, C, D, nullptr, nullptr,
                                                cx0, cy0, n, NBH, 0);
  // pass 1: bits [8,16): B->A, D->C (u64)
  hist64<<<2 * NBH, THREADS, 0, stream>>>(B, D, cx1, cy1, n, NBH, 8);
  scan_both<<<2 * NS8, 256, 0, stream>>>(cx1, cy1, L8, NS8, desc + 2 * NS8,
                                         desc + 3 * NS8);
  scatter_k<0><<<2 * NBH, THREADS, 0, stream>>>(B, A, D, C, nullptr, nullptr,
                                                cx1, cy1, n, NBH, 8);
  // pass 2: bits [16,24): A->B(u32 packed), C->D(u32 packed)
  hist64<<<2 * NBH, THREADS, 0, stream>>>(A, C, cx0, cy0, n, NBH, 16);
  scan_both<<<2 * NS8, 256, 0, stream>>>(cx0, cy0, L8, NS8, desc + 4 * NS8,
                                         desc + 5 * NS8);
  scatter_k<1><<<2 * NBH, THREADS, 0, stream>>>(A, B, C, D, nullptr, nullptr,
                                                cx0, cy0, n, NBH, 16);
  // pass 3: bits [24,30) (packed as v>>21): B(u32)->idx_x, D(u32)->idx_y
  hist32<<<2 * NBH, THREADS, 0, stream>>>((unsigned int*)B, (unsigned int*)D,
                                          cx1, cy1, n, NBH);
  scan_both<<<2 * NS6, 256, 0, stream>>>(cx1, cy1, L6, NS6, desc + 6 * NS8,
                                         desc + 7 * NS8);
  scatter_k<2><<<2 * NBH, THREADS, 0, stream>>>(B, A, D, C, idx_x, idx_y,
                                                cx1, cy1, n, NBH, 0);
}